// Round 4
// baseline (85.568 us; speedup 1.0000x reference)
//
#include <hip/hip_runtime.h>
#include <math.h>

#define BB 32
#define CC 1024
#define NN 4096
#define NCH 16          // n-chunks per row
#define CHK 256         // points per chunk

typedef unsigned long long u64;
typedef __attribute__((ext_vector_type(2))) float f32x2;

// Monotone float encoding: key order == (value asc, smaller index wins ties via
// larger (4095-idx)). All finite floats map to mono > 0.
__device__ __forceinline__ u64 enc_key(float v, int gidx) {
    unsigned u = __float_as_uint(v);
    unsigned mono = (u & 0x80000000u) ? ~u : (u | 0x80000000u);
    return ((u64)mono << 12) | (unsigned)(4095 - gidx);
}

// ---------------------------------------------------------------------------
// K1: per-(b,chunk) partial argmax over 1024 channels (4 per thread) + copy of
// the x chunk to out_x. Wave-uniform x addresses -> L1-broadcast loads.
// Packed-fp32 VOP3P (v_pk_mul_f32 / v_pk_fma_f32) via inline asm -> 2 fp32
// ops per VALU issue slot for the mul/fma chain. NOTE: v_pk_max_f32 does NOT
// exist on gfx950 (round-3 compile error) -> group max stays scalar fmaxf
// tree (clang fuses to v_max3_f32). Each pk half is the same IEEE fp32 op as
// the scalar path, so results (and the scalar recompute epilogue comparisons)
// are bit-identical. grid = 32*16 = 512 blocks x 256 threads.
// ---------------------------------------------------------------------------
__global__ __launch_bounds__(256) void k1_argmax_partial(
    const float* __restrict__ x, const float* __restrict__ W,
    float* __restrict__ out_x, u64* __restrict__ pkeys) {
    const int bid = blockIdx.x;
    const int b = bid >> 4, k = bid & 15;
    const int tid = threadIdx.x;

    if (tid < 192) {
        int d = tid >> 6;
        int off = (tid & 63) << 2;
        const size_t p = (size_t)(b * 3 + d) * NN + k * CHK + off;
        *(float4*)(out_x + p) = *(const float4*)(x + p);
    }

    // W coefficients, splatted into both halves of a VGPR pair for pk ops
    f32x2 wp0[4], wp1[4], wp2[4];
    #pragma unroll
    for (int q = 0; q < 4; ++q) {
        int c = q * 256 + tid;
        float w0 = W[c * 3 + 0], w1 = W[c * 3 + 1], w2 = W[c * 3 + 2];
        wp0[q] = (f32x2){w0, w0};
        wp1[q] = (f32x2){w1, w1};
        wp2[q] = (f32x2){w2, w2};
    }

    const float* xb = x + (size_t)b * 3 * NN + k * CHK;
    float best[4] = {-INFINITY, -INFINITY, -INFINITY, -INFINITY};
    int gn[4] = {0, 0, 0, 0};

    #pragma unroll 4
    for (int n = 0; n < CHK; n += 4) {
        float4 a0 = *(const float4*)(xb + n);
        float4 a1 = *(const float4*)(xb + NN + n);
        float4 a2 = *(const float4*)(xb + 2 * NN + n);
        f32x2 a0lo = (f32x2){a0.x, a0.y}, a0hi = (f32x2){a0.z, a0.w};
        f32x2 a1lo = (f32x2){a1.x, a1.y}, a1hi = (f32x2){a1.z, a1.w};
        f32x2 a2lo = (f32x2){a2.x, a2.y}, a2hi = (f32x2){a2.z, a2.w};
        #pragma unroll
        for (int q = 0; q < 4; ++q) {
            // lo pair: {v0,v1}; hi pair: {v2,v3}; per-half math identical to
            // fmaf(w2,a2, fmaf(w1,a1, w0*a0)) of the verified scalar rounds.
            f32x2 tlo, thi, vlo, vhi;
            asm("v_pk_mul_f32 %0, %1, %2"
                : "=v"(tlo) : "v"(wp0[q]), "v"(a0lo));
            asm("v_pk_fma_f32 %0, %1, %2, %3"
                : "=v"(tlo) : "v"(wp1[q]), "v"(a1lo), "v"(tlo));
            asm("v_pk_fma_f32 %0, %1, %2, %3"
                : "=v"(vlo) : "v"(wp2[q]), "v"(a2lo), "v"(tlo));
            asm("v_pk_mul_f32 %0, %1, %2"
                : "=v"(thi) : "v"(wp0[q]), "v"(a0hi));
            asm("v_pk_fma_f32 %0, %1, %2, %3"
                : "=v"(thi) : "v"(wp1[q]), "v"(a1hi), "v"(thi));
            asm("v_pk_fma_f32 %0, %1, %2, %3"
                : "=v"(vhi) : "v"(wp2[q]), "v"(a2hi), "v"(thi));
            // scalar 4-way max tree (v_pk_max_f32 does not exist on gfx950)
            float gm = fmaxf(fmaxf(vlo.x, vlo.y), fmaxf(vhi.x, vhi.y)); // exact
            if (gm > best[q]) { best[q] = gm; gn[q] = n; }    // first group wins
        }
    }

    #pragma unroll
    for (int q = 0; q < 4; ++q) {
        int n = gn[q];
        float4 a0 = *(const float4*)(xb + n);
        float4 a1 = *(const float4*)(xb + NN + n);
        float4 a2 = *(const float4*)(xb + 2 * NN + n);
        float w0 = wp0[q].x, w1 = wp1[q].x, w2 = wp2[q].x;
        float v0 = fmaf(w2, a2.x, fmaf(w1, a1.x, w0 * a0.x));
        float v1 = fmaf(w2, a2.y, fmaf(w1, a1.y, w0 * a0.y));
        float v2 = fmaf(w2, a2.z, fmaf(w1, a1.z, w0 * a0.z));
        int j = (v0 == best[q]) ? 0 : (v1 == best[q]) ? 1 : (v2 == best[q]) ? 2 : 3;
        pkeys[(size_t)(b * NCH + k) * CC + q * 256 + tid] =
            enc_key(best[q], k * CHK + n + j);
    }
}

// ---------------------------------------------------------------------------
// K2: per-row mega-kernel incl. placement. grid = 32 blocks x 1024 threads.
// Same as round-3 source (round-2 verified + vectorized LDS zeroing).
// ---------------------------------------------------------------------------
__global__ __launch_bounds__(1024) void k2_row_all(
    const u64* __restrict__ pkeys, float* __restrict__ counts,
    float* __restrict__ imp2, float* __restrict__ ent) {
    __shared__ __align__(16) int   cnt[NN];           // 16 KB: counts per point
    __shared__ __align__(16) int   H[NCH * (CC + 1)]; // 65.6 KB: hist/cursors
    __shared__ int   exvs[CC + 1];          // 4.1 KB: exclusive value prefix
    __shared__ float imp2s[NN];             // 16 KB: staged imp2 row
    __shared__ int   wsum[16];
    __shared__ float esum[16];

    const int b = blockIdx.x;
    const int tid = threadIdx.x;
    const int wv = tid >> 6, lane = tid & 63;

    // 1. zero (vectorized: 1 + 4 ds_write_b128 per thread + 16-int tail)
    {
        const int4 z4 = {0, 0, 0, 0};
        *(int4*)(cnt + 4 * tid) = z4;
        #pragma unroll
        for (int i = 0; i < 4; ++i)
            *(int4*)(H + 4 * (i * 1024 + tid)) = z4;  // 16384 of 16400
        if (tid < NCH * (CC + 1) - 16 * 1024) H[16 * 1024 + tid] = 0;
    }
    __syncthreads();

    // 2. combine 16 partial keys for channel c = tid -> winner -> LDS hist
    {
        u64 bestk = 0;
        const u64* pk = pkeys + (size_t)b * NCH * CC + tid;
        #pragma unroll
        for (int k = 0; k < NCH; ++k) {
            u64 key = pk[k * CC];
            bestk = (key > bestk) ? key : bestk;
        }
        int idx = 4095 - (int)(bestk & 0xFFFu);
        atomicAdd(&cnt[idx], 1);
    }
    __syncthreads();

    // 3. write counts (coalesced float4) + per-chunk hist (wave w <-> chunk w)
    {
        float4 cf;
        cf.x = (float)cnt[4 * tid + 0];
        cf.y = (float)cnt[4 * tid + 1];
        cf.z = (float)cnt[4 * tid + 2];
        cf.w = (float)cnt[4 * tid + 3];
        *(float4*)(counts + (size_t)b * NN + 4 * tid) = cf;

        int h0 = 0, h1 = 0;
        #pragma unroll
        for (int r = 0; r < 4; ++r) {
            int ci = cnt[wv * CHK + r * 64 + lane];
            u64 m0 = __ballot(ci == 0);
            u64 m1 = __ballot(ci == 1);
            if (lane == 0) { h0 += (int)__popcll(m0); h1 += (int)__popcll(m1); }
            if (ci > 1) atomicAdd(&H[wv * (CC + 1) + ci], 1);
        }
        if (lane == 0) {           // bins 0/1 never touched by the atomics
            H[wv * (CC + 1) + 0] = h0;
            H[wv * (CC + 1) + 1] = h1;
        }
    }
    __syncthreads();

    // 4. transform H[w][v] -> prefix over chunks (per value v=tid); row total
    //    g_v; entropy partial; wave-level shuffle scan + reduce (no barriers)
    int g_v, run1024 = 0;
    {
        int run = 0;
        #pragma unroll
        for (int w = 0; w < NCH; ++w) {
            int t = H[w * (CC + 1) + tid];
            H[w * (CC + 1) + tid] = run;     // prefix of chunks < w
            run += t;
        }
        g_v = run;
        if (tid == 0) {                      // value bin 1024 handled by thread 0
            int run2 = 0;
            #pragma unroll
            for (int w = 0; w < NCH; ++w) {
                int t = H[w * (CC + 1) + CC];
                H[w * (CC + 1) + CC] = run2;
                run2 += t;
            }
            run1024 = run2;
        }
    }
    const float S = 1024.0f + 4096.0f * 1e-6f;   // sum(counts)+N*eps exactly
    float e = 0.f;
    if (g_v) {
        float p = ((float)tid + 1e-6f) / S;
        e = (float)g_v * p * log2f(p);
    }
    if (tid == 0 && run1024) {
        float p = (1024.0f + 1e-6f) / S;
        e += (float)run1024 * p * log2f(p);
    }
    int incl = g_v;                              // wave inclusive scan
    #pragma unroll
    for (int d = 1; d < 64; d <<= 1) {
        int t = __shfl_up(incl, d, 64);
        if (lane >= d) incl += t;
    }
    float er = e;                                // wave entropy reduce
    #pragma unroll
    for (int d = 32; d > 0; d >>= 1)
        er += __shfl_down(er, d, 64);
    if (lane == 63) wsum[wv] = incl;
    if (lane == 0)  esum[wv] = er;
    __syncthreads();

    // 5. wave0: exclusive scan of 16 wave sums; wave1: entropy total -> ent[b]
    if (wv == 0) {
        int v = (lane < 16) ? wsum[lane] : 0;
        int inc2 = v;
        #pragma unroll
        for (int d = 1; d < 16; d <<= 1) {
            int t = __shfl_up(inc2, d, 64);
            if (lane >= d) inc2 += t;
        }
        if (lane < 16) wsum[lane] = inc2 - v;    // exclusive wave prefix
    } else if (wv == 1) {
        float v = (lane < 16) ? esum[lane] : 0.f;
        #pragma unroll
        for (int d = 8; d > 0; d >>= 1)
            v += __shfl_down(v, d, 64);
        if (lane == 0) ent[b] = -v / 12.0f;      // log2(4096) = 12
    }
    __syncthreads();

    // 6. exclusive value prefix -> LDS
    exvs[tid] = incl - g_v + wsum[wv];
    if (tid == 0) exvs[CC] = NN - run1024;
    __syncthreads();

    // 7. stable placement into LDS staging: wave w <-> chunk w; 4 batches of
    //    64 points in index order. Rank among equals within batch via ballot
    //    match-any; rank across batches via per-(chunk,value) cursor in H.
    {
        const u64 ltmask = (1ull << lane) - 1ull;
        int* curw = &H[wv * (CC + 1)];
        for (int r = 0; r < 4; ++r) {
            const int n = wv * CHK + r * 64 + lane;
            const int ci = cnt[n];
            // match-any: eq = mask of lanes whose ci equals mine
            u64 eq = 0, todo = ~0ull;
            while (true) {                        // ~#distinct values iterations
                int src = (int)__builtin_ctzll(todo);
                int v0 = __shfl(ci, src, 64);
                u64 m = __ballot(ci == v0);
                if (ci == v0) eq = m;
                todo &= ~m;
                if (todo == 0ull) break;
            }
            int rank = (int)__popcll(eq & ltmask);
            int c0 = curw[ci];                    // broadcast-ish LDS read
            imp2s[c0 + exvs[ci] + rank] = (float)n;
            if ((eq >> lane) == 1ull)             // highest equal lane updates
                curw[ci] = c0 + (int)__popcll(eq);
        }
    }
    __syncthreads();

    // 8. coalesced write of the staged imp2 row. Stride-1024 read-out:
    //    consecutive lanes -> consecutive LDS banks (conflict-free) and
    //    fully-coalesced global dword stores.
    {
        float* orow = imp2 + (size_t)b * NN;
        #pragma unroll
        for (int i = 0; i < 4; ++i)
            orow[tid + i * 1024] = imp2s[tid + i * 1024];
    }
}

extern "C" void kernel_launch(void* const* d_in, const int* in_sizes, int n_in,
                              void* d_out, int out_size, void* d_ws, size_t ws_size,
                              hipStream_t stream) {
    const float* x = (const float*)d_in[0];    // [32,3,4096]
    const float* W = (const float*)d_in[1];    // [1024,3]
    float* out    = (float*)d_out;
    float* out_x  = out;                        // 393216
    float* counts = out + (size_t)BB * 3 * NN;  // 131072
    float* imp2   = counts + (size_t)BB * NN;   // 131072
    float* ent    = imp2 + (size_t)BB * NN;     // 32

    u64* pkeys = (u64*)d_ws;                    // 32*16*1024 u64 = 4 MB

    k1_argmax_partial<<<BB * NCH, 256, 0, stream>>>(x, W, out_x, pkeys);
    k2_row_all<<<BB, 1024, 0, stream>>>(pkeys, counts, imp2, ent);
}

// Round 5
// 83.707 us; speedup vs baseline: 1.0222x; 1.0222x over previous
//
#include <hip/hip_runtime.h>
#include <math.h>

#define BB 32
#define CC 1024
#define NN 4096
#define NCH 16          // n-chunks per row
#define CHK 256         // points per chunk

typedef unsigned long long u64;
typedef __attribute__((ext_vector_type(2))) float f32x2;

// Monotone float encoding: key order == (value asc, smaller index wins ties via
// larger (4095-idx)). All finite floats map to mono > 0.
__device__ __forceinline__ u64 enc_key(float v, int gidx) {
    unsigned u = __float_as_uint(v);
    unsigned mono = (u & 0x80000000u) ? ~u : (u | 0x80000000u);
    return ((u64)mono << 12) | (unsigned)(4095 - gidx);
}

// ---------------------------------------------------------------------------
// K1: per-(b,chunk) partial argmax over 1024 channels (4 per thread) + copy of
// the x chunk to out_x. Wave-uniform x addresses -> L1-broadcast loads.
// Round-5 change (k1 only): packed fp32 via COMPILER-NATIVE vector ops
// (__builtin_elementwise_fma on f32x2 -> llvm.fma.v2f32 -> v_pk_fma_f32).
// Round-4's inline-asm variant regressed +4.4us: opaque asm blocks blocked
// scheduling and forced v_mov pair-packing. Native vector ops let the
// scheduler interleave and reuse the float4 load regs in place. Each vector
// half is the same IEEE fp32 mul/fma as the verified scalar path ->
// bit-exact (group max, tie-break, epilogue recompute all scalar/unchanged).
// grid = 32*16 = 512 blocks x 256 threads.
// ---------------------------------------------------------------------------
__global__ __launch_bounds__(256) void k1_argmax_partial(
    const float* __restrict__ x, const float* __restrict__ W,
    float* __restrict__ out_x, u64* __restrict__ pkeys) {
    const int bid = blockIdx.x;
    const int b = bid >> 4, k = bid & 15;
    const int tid = threadIdx.x;

    if (tid < 192) {
        int d = tid >> 6;
        int off = (tid & 63) << 2;
        const size_t p = (size_t)(b * 3 + d) * NN + k * CHK + off;
        *(float4*)(out_x + p) = *(const float4*)(x + p);
    }

    // W coefficients, splatted into both halves for packed ops
    f32x2 wp0[4], wp1[4], wp2[4];
    #pragma unroll
    for (int q = 0; q < 4; ++q) {
        int c = q * 256 + tid;
        float w0 = W[c * 3 + 0], w1 = W[c * 3 + 1], w2 = W[c * 3 + 2];
        wp0[q] = (f32x2){w0, w0};
        wp1[q] = (f32x2){w1, w1};
        wp2[q] = (f32x2){w2, w2};
    }

    const float* xb = x + (size_t)b * 3 * NN + k * CHK;
    float best[4] = {-INFINITY, -INFINITY, -INFINITY, -INFINITY};
    int gn[4] = {0, 0, 0, 0};

    #pragma unroll 4
    for (int n = 0; n < CHK; n += 4) {
        float4 a0 = *(const float4*)(xb + n);
        float4 a1 = *(const float4*)(xb + NN + n);
        float4 a2 = *(const float4*)(xb + 2 * NN + n);
        f32x2 a0lo = (f32x2){a0.x, a0.y}, a0hi = (f32x2){a0.z, a0.w};
        f32x2 a1lo = (f32x2){a1.x, a1.y}, a1hi = (f32x2){a1.z, a1.w};
        f32x2 a2lo = (f32x2){a2.x, a2.y}, a2hi = (f32x2){a2.z, a2.w};
        #pragma unroll
        for (int q = 0; q < 4; ++q) {
            // lo pair {v0,v1}, hi pair {v2,v3}; per-half math identical to
            // fmaf(w2,a2, fmaf(w1,a1, w0*a0)) of the verified scalar rounds.
            f32x2 vlo = __builtin_elementwise_fma(
                wp2[q], a2lo,
                __builtin_elementwise_fma(wp1[q], a1lo, wp0[q] * a0lo));
            f32x2 vhi = __builtin_elementwise_fma(
                wp2[q], a2hi,
                __builtin_elementwise_fma(wp1[q], a1hi, wp0[q] * a0hi));
            // scalar 4-way max tree (no pk_max on gfx950) -- exact
            float gm = fmaxf(fmaxf(vlo.x, vlo.y), fmaxf(vhi.x, vhi.y));
            if (gm > best[q]) { best[q] = gm; gn[q] = n; }    // first group wins
        }
    }

    #pragma unroll
    for (int q = 0; q < 4; ++q) {
        int n = gn[q];
        float4 a0 = *(const float4*)(xb + n);
        float4 a1 = *(const float4*)(xb + NN + n);
        float4 a2 = *(const float4*)(xb + 2 * NN + n);
        float w0 = wp0[q].x, w1 = wp1[q].x, w2 = wp2[q].x;
        float v0 = fmaf(w2, a2.x, fmaf(w1, a1.x, w0 * a0.x));
        float v1 = fmaf(w2, a2.y, fmaf(w1, a1.y, w0 * a0.y));
        float v2 = fmaf(w2, a2.z, fmaf(w1, a1.z, w0 * a0.z));
        int j = (v0 == best[q]) ? 0 : (v1 == best[q]) ? 1 : (v2 == best[q]) ? 2 : 3;
        pkeys[(size_t)(b * NCH + k) * CC + q * 256 + tid] =
            enc_key(best[q], k * CHK + n + j);
    }
}

// ---------------------------------------------------------------------------
// K2: per-row mega-kernel incl. placement. grid = 32 blocks x 1024 threads.
// Byte-identical to round-4 (staging + vectorized zeroing, both >=neutral).
// ---------------------------------------------------------------------------
__global__ __launch_bounds__(1024) void k2_row_all(
    const u64* __restrict__ pkeys, float* __restrict__ counts,
    float* __restrict__ imp2, float* __restrict__ ent) {
    __shared__ __align__(16) int   cnt[NN];           // 16 KB: counts per point
    __shared__ __align__(16) int   H[NCH * (CC + 1)]; // 65.6 KB: hist/cursors
    __shared__ int   exvs[CC + 1];          // 4.1 KB: exclusive value prefix
    __shared__ float imp2s[NN];             // 16 KB: staged imp2 row
    __shared__ int   wsum[16];
    __shared__ float esum[16];

    const int b = blockIdx.x;
    const int tid = threadIdx.x;
    const int wv = tid >> 6, lane = tid & 63;

    // 1. zero (vectorized: 1 + 4 ds_write_b128 per thread + 16-int tail)
    {
        const int4 z4 = {0, 0, 0, 0};
        *(int4*)(cnt + 4 * tid) = z4;
        #pragma unroll
        for (int i = 0; i < 4; ++i)
            *(int4*)(H + 4 * (i * 1024 + tid)) = z4;  // 16384 of 16400
        if (tid < NCH * (CC + 1) - 16 * 1024) H[16 * 1024 + tid] = 0;
    }
    __syncthreads();

    // 2. combine 16 partial keys for channel c = tid -> winner -> LDS hist
    {
        u64 bestk = 0;
        const u64* pk = pkeys + (size_t)b * NCH * CC + tid;
        #pragma unroll
        for (int k = 0; k < NCH; ++k) {
            u64 key = pk[k * CC];
            bestk = (key > bestk) ? key : bestk;
        }
        int idx = 4095 - (int)(bestk & 0xFFFu);
        atomicAdd(&cnt[idx], 1);
    }
    __syncthreads();

    // 3. write counts (coalesced float4) + per-chunk hist (wave w <-> chunk w)
    {
        float4 cf;
        cf.x = (float)cnt[4 * tid + 0];
        cf.y = (float)cnt[4 * tid + 1];
        cf.z = (float)cnt[4 * tid + 2];
        cf.w = (float)cnt[4 * tid + 3];
        *(float4*)(counts + (size_t)b * NN + 4 * tid) = cf;

        int h0 = 0, h1 = 0;
        #pragma unroll
        for (int r = 0; r < 4; ++r) {
            int ci = cnt[wv * CHK + r * 64 + lane];
            u64 m0 = __ballot(ci == 0);
            u64 m1 = __ballot(ci == 1);
            if (lane == 0) { h0 += (int)__popcll(m0); h1 += (int)__popcll(m1); }
            if (ci > 1) atomicAdd(&H[wv * (CC + 1) + ci], 1);
        }
        if (lane == 0) {           // bins 0/1 never touched by the atomics
            H[wv * (CC + 1) + 0] = h0;
            H[wv * (CC + 1) + 1] = h1;
        }
    }
    __syncthreads();

    // 4. transform H[w][v] -> prefix over chunks (per value v=tid); row total
    //    g_v; entropy partial; wave-level shuffle scan + reduce (no barriers)
    int g_v, run1024 = 0;
    {
        int run = 0;
        #pragma unroll
        for (int w = 0; w < NCH; ++w) {
            int t = H[w * (CC + 1) + tid];
            H[w * (CC + 1) + tid] = run;     // prefix of chunks < w
            run += t;
        }
        g_v = run;
        if (tid == 0) {                      // value bin 1024 handled by thread 0
            int run2 = 0;
            #pragma unroll
            for (int w = 0; w < NCH; ++w) {
                int t = H[w * (CC + 1) + CC];
                H[w * (CC + 1) + CC] = run2;
                run2 += t;
            }
            run1024 = run2;
        }
    }
    const float S = 1024.0f + 4096.0f * 1e-6f;   // sum(counts)+N*eps exactly
    float e = 0.f;
    if (g_v) {
        float p = ((float)tid + 1e-6f) / S;
        e = (float)g_v * p * log2f(p);
    }
    if (tid == 0 && run1024) {
        float p = (1024.0f + 1e-6f) / S;
        e += (float)run1024 * p * log2f(p);
    }
    int incl = g_v;                              // wave inclusive scan
    #pragma unroll
    for (int d = 1; d < 64; d <<= 1) {
        int t = __shfl_up(incl, d, 64);
        if (lane >= d) incl += t;
    }
    float er = e;                                // wave entropy reduce
    #pragma unroll
    for (int d = 32; d > 0; d >>= 1)
        er += __shfl_down(er, d, 64);
    if (lane == 63) wsum[wv] = incl;
    if (lane == 0)  esum[wv] = er;
    __syncthreads();

    // 5. wave0: exclusive scan of 16 wave sums; wave1: entropy total -> ent[b]
    if (wv == 0) {
        int v = (lane < 16) ? wsum[lane] : 0;
        int inc2 = v;
        #pragma unroll
        for (int d = 1; d < 16; d <<= 1) {
            int t = __shfl_up(inc2, d, 64);
            if (lane >= d) inc2 += t;
        }
        if (lane < 16) wsum[lane] = inc2 - v;    // exclusive wave prefix
    } else if (wv == 1) {
        float v = (lane < 16) ? esum[lane] : 0.f;
        #pragma unroll
        for (int d = 8; d > 0; d >>= 1)
            v += __shfl_down(v, d, 64);
        if (lane == 0) ent[b] = -v / 12.0f;      // log2(4096) = 12
    }
    __syncthreads();

    // 6. exclusive value prefix -> LDS
    exvs[tid] = incl - g_v + wsum[wv];
    if (tid == 0) exvs[CC] = NN - run1024;
    __syncthreads();

    // 7. stable placement into LDS staging: wave w <-> chunk w; 4 batches of
    //    64 points in index order. Rank among equals within batch via ballot
    //    match-any; rank across batches via per-(chunk,value) cursor in H.
    {
        const u64 ltmask = (1ull << lane) - 1ull;
        int* curw = &H[wv * (CC + 1)];
        for (int r = 0; r < 4; ++r) {
            const int n = wv * CHK + r * 64 + lane;
            const int ci = cnt[n];
            // match-any: eq = mask of lanes whose ci equals mine
            u64 eq = 0, todo = ~0ull;
            while (true) {                        // ~#distinct values iterations
                int src = (int)__builtin_ctzll(todo);
                int v0 = __shfl(ci, src, 64);
                u64 m = __ballot(ci == v0);
                if (ci == v0) eq = m;
                todo &= ~m;
                if (todo == 0ull) break;
            }
            int rank = (int)__popcll(eq & ltmask);
            int c0 = curw[ci];                    // broadcast-ish LDS read
            imp2s[c0 + exvs[ci] + rank] = (float)n;
            if ((eq >> lane) == 1ull)             // highest equal lane updates
                curw[ci] = c0 + (int)__popcll(eq);
        }
    }
    __syncthreads();

    // 8. coalesced write of the staged imp2 row. Stride-1024 read-out:
    //    consecutive lanes -> consecutive LDS banks (conflict-free) and
    //    fully-coalesced global dword stores.
    {
        float* orow = imp2 + (size_t)b * NN;
        #pragma unroll
        for (int i = 0; i < 4; ++i)
            orow[tid + i * 1024] = imp2s[tid + i * 1024];
    }
}

extern "C" void kernel_launch(void* const* d_in, const int* in_sizes, int n_in,
                              void* d_out, int out_size, void* d_ws, size_t ws_size,
                              hipStream_t stream) {
    const float* x = (const float*)d_in[0];    // [32,3,4096]
    const float* W = (const float*)d_in[1];    // [1024,3]
    float* out    = (float*)d_out;
    float* out_x  = out;                        // 393216
    float* counts = out + (size_t)BB * 3 * NN;  // 131072
    float* imp2   = counts + (size_t)BB * NN;   // 131072
    float* ent    = imp2 + (size_t)BB * NN;     // 32

    u64* pkeys = (u64*)d_ws;                    // 32*16*1024 u64 = 4 MB

    k1_argmax_partial<<<BB * NCH, 256, 0, stream>>>(x, W, out_x, pkeys);
    k2_row_all<<<BB, 1024, 0, stream>>>(pkeys, counts, imp2, ent);
}

// Round 6
// 80.250 us; speedup vs baseline: 1.0663x; 1.0431x over previous
//
#include <hip/hip_runtime.h>
#include <math.h>

#define BB 32
#define CC 1024
#define NN 4096
#define NCH 16          // n-chunks per row
#define CHK 256         // points per chunk

typedef unsigned long long u64;

// Monotone float encoding: key order == (value asc, smaller index wins ties via
// larger (4095-idx)). All finite floats map to mono > 0.
__device__ __forceinline__ u64 enc_key(float v, int gidx) {
    unsigned u = __float_as_uint(v);
    unsigned mono = (u & 0x80000000u) ? ~u : (u | 0x80000000u);
    return ((u64)mono << 12) | (unsigned)(4095 - gidx);
}

// ---------------------------------------------------------------------------
// K1: per-(b,chunk) partial argmax over 1024 channels (4 per thread) + copy of
// the x chunk to out_x. Wave-uniform x addresses -> scalar/L1-broadcast loads.
// Group-of-4 max trick; winner position resolved by bit-exact recompute.
// grid = 32*16 = 512 blocks x 256 threads.
// RESTORED to the round-0 measured-optimal scalar form. Session evidence:
// scalar 79.9 / 512-thread ~90 / inline-asm pk 85.6 / native-v2f32 pk 83.7.
// Packed-fp32 does not pay on gfx950 for this loop; do not revisit.
// ---------------------------------------------------------------------------
__global__ __launch_bounds__(256) void k1_argmax_partial(
    const float* __restrict__ x, const float* __restrict__ W,
    float* __restrict__ out_x, u64* __restrict__ pkeys) {
    const int bid = blockIdx.x;
    const int b = bid >> 4, k = bid & 15;
    const int tid = threadIdx.x;

    if (tid < 192) {
        int d = tid >> 6;
        int off = (tid & 63) << 2;
        const size_t p = (size_t)(b * 3 + d) * NN + k * CHK + off;
        *(float4*)(out_x + p) = *(const float4*)(x + p);
    }

    float w0[4], w1[4], w2[4];
    #pragma unroll
    for (int q = 0; q < 4; ++q) {
        int c = q * 256 + tid;
        w0[q] = W[c * 3 + 0];
        w1[q] = W[c * 3 + 1];
        w2[q] = W[c * 3 + 2];
    }

    const float* xb = x + (size_t)b * 3 * NN + k * CHK;
    float best[4] = {-INFINITY, -INFINITY, -INFINITY, -INFINITY};
    int gn[4] = {0, 0, 0, 0};

    #pragma unroll 4
    for (int n = 0; n < CHK; n += 4) {
        float4 a0 = *(const float4*)(xb + n);
        float4 a1 = *(const float4*)(xb + NN + n);
        float4 a2 = *(const float4*)(xb + 2 * NN + n);
        #pragma unroll
        for (int q = 0; q < 4; ++q) {
            // identical fp contraction to all verified rounds (bit-matched ref)
            float v0 = fmaf(w2[q], a2.x, fmaf(w1[q], a1.x, w0[q] * a0.x));
            float v1 = fmaf(w2[q], a2.y, fmaf(w1[q], a1.y, w0[q] * a0.y));
            float v2 = fmaf(w2[q], a2.z, fmaf(w1[q], a1.z, w0[q] * a0.z));
            float v3 = fmaf(w2[q], a2.w, fmaf(w1[q], a1.w, w0[q] * a0.w));
            float gm = fmaxf(fmaxf(v0, v1), fmaxf(v2, v3));   // exact
            if (gm > best[q]) { best[q] = gm; gn[q] = n; }    // first group wins
        }
    }

    #pragma unroll
    for (int q = 0; q < 4; ++q) {
        int n = gn[q];
        float4 a0 = *(const float4*)(xb + n);
        float4 a1 = *(const float4*)(xb + NN + n);
        float4 a2 = *(const float4*)(xb + 2 * NN + n);
        float v0 = fmaf(w2[q], a2.x, fmaf(w1[q], a1.x, w0[q] * a0.x));
        float v1 = fmaf(w2[q], a2.y, fmaf(w1[q], a1.y, w0[q] * a0.y));
        float v2 = fmaf(w2[q], a2.z, fmaf(w1[q], a1.z, w0[q] * a0.z));
        int j = (v0 == best[q]) ? 0 : (v1 == best[q]) ? 1 : (v2 == best[q]) ? 2 : 3;
        pkeys[(size_t)(b * NCH + k) * CC + q * 256 + tid] =
            enc_key(best[q], k * CHK + n + j);
    }
}

// ---------------------------------------------------------------------------
// K2: per-row mega-kernel incl. placement. grid = 32 blocks x 1024 threads.
// RESTORED to round-0 measured-optimal form (direct global placement writes;
// imp2 LDS staging measured +1.3us in R2 and is removed). Single retained
// delta vs round-0: vectorized LDS zeroing (int4 / ds_write_b128).
// ---------------------------------------------------------------------------
__global__ __launch_bounds__(1024) void k2_row_all(
    const u64* __restrict__ pkeys, float* __restrict__ counts,
    float* __restrict__ imp2, float* __restrict__ ent) {
    __shared__ __align__(16) int   cnt[NN];           // 16 KB: counts per point
    __shared__ __align__(16) int   H[NCH * (CC + 1)]; // 65.6 KB: hist/cursors
    __shared__ int   exvs[CC + 1];          // 4.1 KB: exclusive value prefix
    __shared__ int   wsum[16];
    __shared__ float esum[16];

    const int b = blockIdx.x;
    const int tid = threadIdx.x;
    const int wv = tid >> 6, lane = tid & 63;

    // 1. zero (vectorized: 1 + 4 ds_write_b128 per thread + 16-int tail)
    {
        const int4 z4 = {0, 0, 0, 0};
        *(int4*)(cnt + 4 * tid) = z4;
        #pragma unroll
        for (int i = 0; i < 4; ++i)
            *(int4*)(H + 4 * (i * 1024 + tid)) = z4;  // 16384 of 16400
        if (tid < NCH * (CC + 1) - 16 * 1024) H[16 * 1024 + tid] = 0;
    }
    __syncthreads();

    // 2. combine 16 partial keys for channel c = tid -> winner -> LDS hist
    {
        u64 bestk = 0;
        const u64* pk = pkeys + (size_t)b * NCH * CC + tid;
        #pragma unroll
        for (int k = 0; k < NCH; ++k) {
            u64 key = pk[k * CC];
            bestk = (key > bestk) ? key : bestk;
        }
        int idx = 4095 - (int)(bestk & 0xFFFu);
        atomicAdd(&cnt[idx], 1);
    }
    __syncthreads();

    // 3. write counts (coalesced float4) + per-chunk hist (wave w <-> chunk w)
    {
        float4 cf;
        cf.x = (float)cnt[4 * tid + 0];
        cf.y = (float)cnt[4 * tid + 1];
        cf.z = (float)cnt[4 * tid + 2];
        cf.w = (float)cnt[4 * tid + 3];
        *(float4*)(counts + (size_t)b * NN + 4 * tid) = cf;

        int h0 = 0, h1 = 0;
        #pragma unroll
        for (int r = 0; r < 4; ++r) {
            int ci = cnt[wv * CHK + r * 64 + lane];
            u64 m0 = __ballot(ci == 0);
            u64 m1 = __ballot(ci == 1);
            if (lane == 0) { h0 += (int)__popcll(m0); h1 += (int)__popcll(m1); }
            if (ci > 1) atomicAdd(&H[wv * (CC + 1) + ci], 1);
        }
        if (lane == 0) {           // bins 0/1 never touched by the atomics
            H[wv * (CC + 1) + 0] = h0;
            H[wv * (CC + 1) + 1] = h1;
        }
    }
    __syncthreads();

    // 4. transform H[w][v] -> prefix over chunks (per value v=tid); row total
    //    g_v; entropy partial; wave-level shuffle scan + reduce (no barriers)
    int g_v, run1024 = 0;
    {
        int run = 0;
        #pragma unroll
        for (int w = 0; w < NCH; ++w) {
            int t = H[w * (CC + 1) + tid];
            H[w * (CC + 1) + tid] = run;     // prefix of chunks < w
            run += t;
        }
        g_v = run;
        if (tid == 0) {                      // value bin 1024 handled by thread 0
            int run2 = 0;
            #pragma unroll
            for (int w = 0; w < NCH; ++w) {
                int t = H[w * (CC + 1) + CC];
                H[w * (CC + 1) + CC] = run2;
                run2 += t;
            }
            run1024 = run2;
        }
    }
    const float S = 1024.0f + 4096.0f * 1e-6f;   // sum(counts)+N*eps exactly
    float e = 0.f;
    if (g_v) {
        float p = ((float)tid + 1e-6f) / S;
        e = (float)g_v * p * log2f(p);
    }
    if (tid == 0 && run1024) {
        float p = (1024.0f + 1e-6f) / S;
        e += (float)run1024 * p * log2f(p);
    }
    int incl = g_v;                              // wave inclusive scan
    #pragma unroll
    for (int d = 1; d < 64; d <<= 1) {
        int t = __shfl_up(incl, d, 64);
        if (lane >= d) incl += t;
    }
    float er = e;                                // wave entropy reduce
    #pragma unroll
    for (int d = 32; d > 0; d >>= 1)
        er += __shfl_down(er, d, 64);
    if (lane == 63) wsum[wv] = incl;
    if (lane == 0)  esum[wv] = er;
    __syncthreads();

    // 5. wave0: exclusive scan of 16 wave sums; wave1: entropy total -> ent[b]
    if (wv == 0) {
        int v = (lane < 16) ? wsum[lane] : 0;
        int inc2 = v;
        #pragma unroll
        for (int d = 1; d < 16; d <<= 1) {
            int t = __shfl_up(inc2, d, 64);
            if (lane >= d) inc2 += t;
        }
        if (lane < 16) wsum[lane] = inc2 - v;    // exclusive wave prefix
    } else if (wv == 1) {
        float v = (lane < 16) ? esum[lane] : 0.f;
        #pragma unroll
        for (int d = 8; d > 0; d >>= 1)
            v += __shfl_down(v, d, 64);
        if (lane == 0) ent[b] = -v / 12.0f;      // log2(4096) = 12
    }
    __syncthreads();

    // 6. exclusive value prefix -> LDS
    exvs[tid] = incl - g_v + wsum[wv];
    if (tid == 0) exvs[CC] = NN - run1024;
    __syncthreads();

    // 7. stable placement: wave w <-> chunk w; 4 batches of 64 points in index
    //    order. Rank among equals within batch via ballot match-any; rank
    //    across batches via per-(chunk,value) cursor in H (wave-private row).
    {
        const u64 ltmask = (1ull << lane) - 1ull;
        int* curw = &H[wv * (CC + 1)];
        float* orow = imp2 + (size_t)b * NN;
        for (int r = 0; r < 4; ++r) {
            const int n = wv * CHK + r * 64 + lane;
            const int ci = cnt[n];
            // match-any: eq = mask of lanes whose ci equals mine
            u64 eq = 0, todo = ~0ull;
            while (true) {                        // ~#distinct values iterations
                int src = (int)__builtin_ctzll(todo);
                int v0 = __shfl(ci, src, 64);
                u64 m = __ballot(ci == v0);
                if (ci == v0) eq = m;
                todo &= ~m;
                if (todo == 0ull) break;
            }
            int rank = (int)__popcll(eq & ltmask);
            int c0 = curw[ci];                    // broadcast-ish LDS read
            orow[c0 + exvs[ci] + rank] = (float)n;
            if ((eq >> lane) == 1ull)             // highest equal lane updates
                curw[ci] = c0 + (int)__popcll(eq);
        }
    }
}

extern "C" void kernel_launch(void* const* d_in, const int* in_sizes, int n_in,
                              void* d_out, int out_size, void* d_ws, size_t ws_size,
                              hipStream_t stream) {
    const float* x = (const float*)d_in[0];    // [32,3,4096]
    const float* W = (const float*)d_in[1];    // [1024,3]
    float* out    = (float*)d_out;
    float* out_x  = out;                        // 393216
    float* counts = out + (size_t)BB * 3 * NN;  // 131072
    float* imp2   = counts + (size_t)BB * NN;   // 131072
    float* ent    = imp2 + (size_t)BB * NN;     // 32

    u64* pkeys = (u64*)d_ws;                    // 32*16*1024 u64 = 4 MB

    k1_argmax_partial<<<BB * NCH, 256, 0, stream>>>(x, W, out_x, pkeys);
    k2_row_all<<<BB, 1024, 0, stream>>>(pkeys, counts, imp2, ent);
}